// Round 13
// baseline (248.216 us; speedup 1.0000x reference)
//
#include <hip/hip_runtime.h>
#include <math.h>

// Problem constants
#define B_SZ 2
#define SEQ 512
#define DM 1024
#define DI 2048
#define DS 32
#define TOK (B_SZ*SEQ)        // 1024
#define NCH 8                 // scan chunks (staging granularity only now)
#define CLEN (SEQ/NCH)        // 64

// fused weight layout (rows of K=1024, bf16):
//   [0,4096) W_in | [4096,6144) W_dt | [6144,6176) W_B | [6176,6208) W_C | [6208,6272) pad
#define NFUSED 6272

typedef float v2f __attribute__((ext_vector_type(2)));

__device__ __forceinline__ unsigned short f2bf(float f) {
  unsigned int u = __builtin_bit_cast(unsigned int, f);
  unsigned int r = u + 0x7fffu + ((u >> 16) & 1u);   // RNE (inputs finite)
  return (unsigned short)(r >> 16);
}

// DPP row-rotate add: sums over the 16-lane row with 4 VALU ops (no LDS pipe).
template<int CTRL>
__device__ __forceinline__ float row_ror_add(float x) {
  int s = __builtin_amdgcn_update_dpp(0, __builtin_bit_cast(int, x), CTRL, 0xf, 0xf, false);
  return x + __builtin_bit_cast(float, s);
}
__device__ __forceinline__ float row16_sum(float v) {
  v = row_ror_add<0x121>(v);
  v = row_ror_add<0x122>(v);
  v = row_ror_add<0x124>(v);
  v = row_ror_add<0x128>(v);
  return v;
}

// ---------------- fused fp32 -> bf16 cast of all 6 tensors, 8 elems/thread ----------------
__global__ __launch_bounds__(256) void fused_cast(const float* __restrict__ x,
                                                  const float* __restrict__ W_in,
                                                  const float* __restrict__ W_dt,
                                                  const float* __restrict__ W_B,
                                                  const float* __restrict__ W_C,
                                                  const float* __restrict__ W_out,
                                                  unsigned short* __restrict__ xb,
                                                  unsigned short* __restrict__ wcat,
                                                  unsigned short* __restrict__ wob) {
  int g = blockIdx.x * 256 + threadIdx.x;
  const float* s; unsigned short* dd; int off;
  if      (g <  131072) { s = x;     dd = xb;             off = 0; }
  else if (g <  655360) { s = W_in;  dd = wcat;           off = 131072; }
  else if (g <  917504) { s = W_dt;  dd = wcat + 4194304; off = 655360; }
  else if (g <  921600) { s = W_B;   dd = wcat + 6291456; off = 917504; }
  else if (g <  925696) { s = W_C;   dd = wcat + 6324224; off = 921600; }
  else if (g < 1187840) { s = W_out; dd = wob;            off = 925696; }
  else return;
  int i = g - off;
  float4 a = ((const float4*)s)[i * 2];
  float4 b = ((const float4*)s)[i * 2 + 1];
  union { unsigned short us[8]; uint4 v; } o;
  o.us[0] = f2bf(a.x); o.us[1] = f2bf(a.y); o.us[2] = f2bf(a.z); o.us[3] = f2bf(a.w);
  o.us[4] = f2bf(b.x); o.us[5] = f2bf(b.y); o.us[6] = f2bf(b.z); o.us[7] = f2bf(b.w);
  ((uint4*)dd)[i] = o.v;
}

// ---------------- bf16 MFMA GEMM (C = A * B^T), 64x64 tile, BK=64, XOR-swizzled LDS ----------
typedef __attribute__((ext_vector_type(8))) short  frag8;
typedef __attribute__((ext_vector_type(4))) float  facc4;

__device__ __forceinline__ void gload_lds16(const unsigned short* g, unsigned short* l) {
  __builtin_amdgcn_global_load_lds((const __attribute__((address_space(1))) unsigned int*)g,
                                   (__attribute__((address_space(3))) unsigned int*)l, 16, 0, 0);
}

__device__ __forceinline__ float softplus_fast(float v) {
  return fmaxf(v, 0.f) + __logf(1.f + __expf(-fabsf(v)));
}

// LDS swizzle: row r's k-segment s (8 bf16 = 16 B) lives at segment s^(r&7).
template<int MT, int NT, int KSP, bool ROUTE>
__global__ __launch_bounds__(256) void gemm_mfma(const unsigned short* __restrict__ A,
                                                 const unsigned short* __restrict__ Bw,
                                                 int K,
                                                 float* __restrict__ o_xs,
                                                 float* __restrict__ o_zb,
                                                 float* __restrict__ o_dts,
                                                 float* __restrict__ o_bcb,
                                                 const float* __restrict__ b_dt,
                                                 const float* __restrict__ dt_bias,
                                                 float* __restrict__ o_c, int ldc) {
  __shared__ __align__(16) unsigned short As[64 * 64];   // 8 KB
  __shared__ __align__(16) unsigned short Bs[64 * 64];   // 8 KB
  const int tid = threadIdx.x;
  const int w = tid >> 6, lane = tid & 63;
  const int wm = w >> 1, wn = w & 1;
  const int bid = blockIdx.x;
  const int Wk = (bid & 7) * ((int)gridDim.x >> 3) + (bid >> 3);
  const int ks = Wk / (MT * NT);
  const int rem = Wk % (MT * NT);
  const int m0 = (rem % MT) * 64;
  const int n0 = (rem / MT) * 64;
  const int kLen = K / KSP, kBeg = ks * kLen;
  const int r = lane & 15, q = lane >> 4;
  const int srow = lane >> 3;                         // staging row-in-chunk (0..7)
  const int scol = ((lane & 7) ^ (srow & 7)) * 8;     // XOR-swizzled source k-seg
  facc4 acc[2][2] = {};
  const unsigned short* Ag = A + (size_t)m0 * K + kBeg;
  const unsigned short* Bg = Bw + (size_t)n0 * K + kBeg;

  for (int k0 = 0; k0 < kLen; k0 += 64) {
#pragma unroll
    for (int k = 0; k < 2; ++k) {
      int ch = w * 2 + k;                // 8 chunks of 8 rows x 64 k (1 KB)
      gload_lds16(Ag + (size_t)(ch * 8 + srow) * K + k0 + scol, &As[ch * 512]);
      gload_lds16(Bg + (size_t)(ch * 8 + srow) * K + k0 + scol, &Bs[ch * 512]);
    }
    __syncthreads();                     // drains global_load_lds
#pragma unroll
    for (int kk = 0; kk < 2; ++kk) {
      frag8 af[2], bf[2];
      const int sw = ((kk * 4 + q) ^ (r & 7)) * 8;    // swizzled seg offset
#pragma unroll
      for (int i = 0; i < 2; ++i)
        af[i] = *(const frag8*)&As[(wm * 32 + i * 16 + r) * 64 + sw];
#pragma unroll
      for (int jj = 0; jj < 2; ++jj)
        bf[jj] = *(const frag8*)&Bs[(wn * 32 + jj * 16 + r) * 64 + sw];
#pragma unroll
      for (int i = 0; i < 2; ++i)
#pragma unroll
        for (int jj = 0; jj < 2; ++jj)
          acc[i][jj] = __builtin_amdgcn_mfma_f32_16x16x32_bf16(af[i], bf[jj], acc[i][jj], 0, 0, 0);
    }
    __syncthreads();
  }

#pragma unroll
  for (int i = 0; i < 2; ++i) {
#pragma unroll
    for (int jj = 0; jj < 2; ++jj) {
      int n = n0 + wn * 32 + jj * 16 + r;
      int mb = m0 + wm * 32 + i * 16 + q * 4;
      if (ROUTE) {
        if (n < 2048) {
#pragma unroll
          for (int rg = 0; rg < 4; ++rg)
            o_xs[(size_t)(mb + rg) * DI + n] = acc[i][jj][rg];
        } else if (n < 4096) {
#pragma unroll
          for (int rg = 0; rg < 4; ++rg)
            o_zb[(size_t)(mb + rg) * DI + (n - 2048)] = acc[i][jj][rg];
        } else if (n < 6144) {
          int d = n - 4096;
          float bias = b_dt[d] + dt_bias[d];
#pragma unroll
          for (int rg = 0; rg < 4; ++rg)
            o_dts[(size_t)(mb + rg) * DI + d] = softplus_fast(acc[i][jj][rg] + bias);
        } else if (n < 6176) {
#pragma unroll
          for (int rg = 0; rg < 4; ++rg)
            o_bcb[(size_t)(mb + rg) * DS + (n - 6144)] = acc[i][jj][rg];
        } else if (n < 6208) {
#pragma unroll
          for (int rg = 0; rg < 4; ++rg)
            o_bcb[(size_t)TOK * DS + (size_t)(mb + rg) * DS + (n - 6176)] = acc[i][jj][rg];
        }
      } else {
        float* oc = o_c + (size_t)ks * (MT * 64) * ldc;
#pragma unroll
        for (int rg = 0; rg < 4; ++rg)
          oc[(size_t)(mb + rg) * ldc + n] = acc[i][jj][rg];
      }
    }
  }
}

// ---------------- split-K reduction: out = P0 + P1 (float4) ----------------
__global__ __launch_bounds__(256) void addk(const float* __restrict__ p0,
                                            const float* __restrict__ p1,
                                            float* __restrict__ o) {
  int i = blockIdx.x * 256 + threadIdx.x;
  float4 a = ((const float4*)p0)[i];
  float4 b = ((const float4*)p1)[i];
  ((float4*)o)[i] = make_float4(a.x + b.x, a.y + b.y, a.z + b.z, a.w + b.w);
}

// ---------------- single-pass persistent scan ----------------
// 128 blocks (b x 64 channel-groups of 32), 256 threads, all 512 steps sequential per block.
// Double-buffered LDS (2 x 32 KB): x @0 | dt @2048 | B @4096 | C @6144 (floats, per buffer).
// Chunk c+1 is fetched into VGPRs before computing chunk c (latency hidden by ~3000 cy of
// compute), then ds_write-staged after compute — avoids the global_load_lds vmcnt(0) drain.
// Lane: j = tid&15 (DPP row pos), ca = (tid>>4)&15; v2f chains d = dbase+2*ca, +1.

__device__ __forceinline__ void scan_load_chunk(const float* __restrict__ xs,
                                                const float* __restrict__ dts,
                                                const float* __restrict__ bcb,
                                                int b, int c, int dbase, int tid,
                                                float4* pre) {
  const size_t base = (size_t)(b * SEQ + c * CLEN);
#pragma unroll
  for (int k = 0; k < 2; ++k) {
    int idx = tid * 2 + k;              // 0..511
    int row = idx >> 3, c4 = (idx & 7) * 4;
    pre[k]     = *(const float4*)(xs  + (base + row) * DI + dbase + c4);
    pre[2 + k] = *(const float4*)(dts + (base + row) * DI + dbase + c4);
    pre[4 + k] = ((const float4*)(bcb + base * DS))[idx];
    pre[6 + k] = ((const float4*)(bcb + (size_t)TOK * DS + base * DS))[idx];
  }
}

__device__ __forceinline__ void scan_write_chunk(float* __restrict__ bb, int tid,
                                                 const float4* pre) {
#pragma unroll
  for (int k = 0; k < 2; ++k) {
    int idx = tid * 2 + k;
    *(float4*)(bb + idx * 4)        = pre[k];       // x
    *(float4*)(bb + 2048 + idx * 4) = pre[2 + k];   // dt
    *(float4*)(bb + 4096 + idx * 4) = pre[4 + k];   // B
    *(float4*)(bb + 6144 + idx * 4) = pre[6 + k];   // C
  }
}

__device__ __forceinline__ void scan_chunk(const float* __restrict__ bb,
                                           float* __restrict__ yp, int ca, int j,
                                           v2f Ar, v2f Ai, float cF, float sF,
                                           v2f& sr, v2f& si, float& cs, float& sn) {
#pragma unroll 4
  for (int tt = 0; tt < CLEN; ++tt) {
    const int ro = tt * 32;
    v2f xin = *(const v2f*)&bb[ro + 2 * ca];
    v2f dtd = *(const v2f*)&bb[2048 + ro + 2 * ca];
    float Br = bb[4096 + ro + j];
    float Bi = bb[4096 + ro + j + 16];
    float Cr = bb[6144 + ro + j];
    float Ci = bb[6144 + ro + j + 16];
    v2f hr = dtd * Ar, hi = dtd * Ai;
    v2f invr, invi;
    invr.x = __builtin_amdgcn_rcpf(1.f - hr.x);
    invr.y = __builtin_amdgcn_rcpf(1.f - hr.y);
    invi.x = __builtin_amdgcn_rcpf(1.f - hi.x);
    invi.y = __builtin_amdgcn_rcpf(1.f - hi.y);
    v2f Abr = 2.f * invr - 1.f;         // (1+h)/(1-h)
    v2f Abi = 2.f * invi - 1.f;
    v2f dx = dtd * xin;
    v2f bxr = dx * invr * Br;
    v2f bxi = dx * invi * Bi;
    v2f tr = Abr * sr + bxr;
    v2f ti = Abi * si + bxi;
    sr = tr * cs - ti * sn;
    si = tr * sn + ti * cs;
    v2f p = sr * Cr + si * Ci;
    float pA = row16_sum(p.x);
    float pB = row16_sum(p.y);
    if (j == 0) *(float2*)&yp[tt * DI] = make_float2(pA, pB);
    float nc = fmaf(cs, cF, -sn * sF);
    float ns = fmaf(sn, cF,  cs * sF);
    cs = nc; sn = ns;
  }
}

__global__ __launch_bounds__(256) void scan_seq(const float* __restrict__ xs,
                                                const float* __restrict__ dts,
                                                const float* __restrict__ bcb,
                                                const float* __restrict__ A_log,
                                                const float* __restrict__ rope,
                                                float* __restrict__ y,
                                                float* __restrict__ fstate) {
  __shared__ __align__(16) float lds[16384];   // 64 KB, two 32 KB buffers
  const int blk = blockIdx.x;           // 128
  const int b = blk >> 6;
  const int dbase = (blk & 63) << 5;
  const int tid = threadIdx.x;
  const int j = tid & 15;
  const int ca = (tid >> 4) & 15;
  const int dA = dbase + 2 * ca;

  v2f Ar, Ai;
  Ar.x = -0.5f * expf(A_log[dA * DS + j]);
  Ar.y = -0.5f * expf(A_log[(dA + 1) * DS + j]);
  Ai.x = -0.5f * expf(A_log[dA * DS + j + 16]);
  Ai.y = -0.5f * expf(A_log[(dA + 1) * DS + j + 16]);
  const float fr = rope[j];
  float sF, cF;
  sincosf(fr, &sF, &cF);
  float cs = 1.f, sn = 0.f;             // rotation at l=0
  v2f sr = {0.f, 0.f}, si = {0.f, 0.f};

  float4 pre[8];
  // prologue: stage chunk 0
  scan_load_chunk(xs, dts, bcb, b, 0, dbase, tid, pre);
  scan_write_chunk(lds, tid, pre);
  __syncthreads();

  for (int c = 0; c < NCH; ++c) {
    if (c + 1 < NCH)
      scan_load_chunk(xs, dts, bcb, b, c + 1, dbase, tid, pre);   // loads in flight
    float* bb = lds + (c & 1) * 8192;
    float* yp = y + (size_t)(b * SEQ + c * CLEN) * DI + dA;
    scan_chunk(bb, yp, ca, j, Ar, Ai, cF, sF, sr, si, cs, sn);
    if (c + 1 < NCH) {
      scan_write_chunk(lds + ((c + 1) & 1) * 8192, tid, pre);     // vmcnt wait here (satisfied)
      __syncthreads();
    }
  }

  fstate[((size_t)b * DI + dA) * DS + j]          = sr.x;
  fstate[((size_t)b * DI + dA) * DS + j + 16]     = si.x;
  fstate[((size_t)b * DI + dA + 1) * DS + j]      = sr.y;
  fstate[((size_t)b * DI + dA + 1) * DS + j + 16] = si.y;
}

// ---------------- gate (y * silu(z)) + LayerNorm, bf16 output ----------------
__global__ __launch_bounds__(256) void gate_ln(const float* __restrict__ y,
                                               const float* __restrict__ zb,
                                               const float* __restrict__ lw,
                                               const float* __restrict__ lb,
                                               unsigned short* __restrict__ o) {
  int tok = blockIdx.x;
  int t = threadIdx.x;
  float g[8];
  float sum = 0.f, sq = 0.f;
#pragma unroll
  for (int i = 0; i < 8; ++i) {
    int dd = t + i * 256;
    float yv = y[(size_t)tok * DI + dd];
    float zv = zb[(size_t)tok * DI + dd];
    float sg = zv / (1.f + __expf(-zv));
    float v = yv * sg;
    g[i] = v; sum += v; sq += v * v;
  }
#pragma unroll
  for (int off = 32; off; off >>= 1) { sum += __shfl_xor(sum, off); sq += __shfl_xor(sq, off); }
  __shared__ float rs[4], rq[4];
  int w = t >> 6;
  if ((t & 63) == 0) { rs[w] = sum; rq[w] = sq; }
  __syncthreads();
  sum = rs[0] + rs[1] + rs[2] + rs[3];
  sq  = rq[0] + rq[1] + rq[2] + rq[3];
  float mu = sum * (1.f / DI);
  float var = sq * (1.f / DI) - mu * mu;
  float rstd = rsqrtf(var + 1e-5f);
#pragma unroll
  for (int i = 0; i < 8; ++i) {
    int dd = t + i * 256;
    o[(size_t)tok * DI + dd] = f2bf((g[i] - mu) * rstd * lw[dd] + lb[dd]);
  }
}

// ---------------- launch ----------------
extern "C" void kernel_launch(void* const* d_in, const int* in_sizes, int n_in,
                              void* d_out, int out_size, void* d_ws, size_t ws_size,
                              hipStream_t stream) {
  const float* x       = (const float*)d_in[0];
  const float* W_in    = (const float*)d_in[1];
  const float* A_log   = (const float*)d_in[2];
  const float* W_B     = (const float*)d_in[3];
  const float* W_C     = (const float*)d_in[4];
  const float* W_dt    = (const float*)d_in[5];
  const float* b_dt    = (const float*)d_in[6];
  const float* dt_bias = (const float*)d_in[7];
  const float* rope    = (const float*)d_in[8];
  const float* ln_w    = (const float*)d_in[9];
  const float* ln_b    = (const float*)d_in[10];
  const float* W_out   = (const float*)d_in[11];
  float* out = (float*)d_out;
  float* ws = (float*)d_ws;

  // workspace layout (float offsets); overlays noted
  float* xs   = ws;                                   // [0, 2097152)
  float* zb   = ws + 2097152;                         // [2097152, 4194304)
  float* dts  = ws + 4194304;                         // [4194304, 6291456)
  float* bcb  = ws + 6291456;                         // [6291456, 6356992)
  unsigned short* wob  = (unsigned short*)(ws + 6356992);  // 2M bf16   [.., 7405568)
  unsigned short* xb   = (unsigned short*)(ws + 7405568);  // 1M bf16   [.., 7929856)
  unsigned short* wcat = (unsigned short*)(ws + 7929856);  // 6.42M bf16 [.., 11141120)
  float* yb   = ws + 11141120;                        // 2097152 f  [.., 13238272)
  unsigned short* lnb = (unsigned short*)(ws + 13238272);  // 2M bf16 [.., 14286848)
  float* Pk   = ws;                                   // split-K partials, alias xs (dead after scan)
  float* fstate = out + (size_t)TOK * DM;

  // 1) fused bf16 casts (x, W_in, W_dt, W_B, W_C, W_out)
  fused_cast<<<4640, 256, 0, stream>>>(x, W_in, W_dt, W_B, W_C, W_out, xb, wcat, wob);
  // 2) fused input GEMM, 64x64 tiles, BK=64, swizzled LDS, 1568 blocks, XCD-swizzled
  gemm_mfma<16, 98, 1, true><<<16 * 98, 256, 0, stream>>>(
      xb, wcat, DM, xs, zb, dts, bcb, b_dt, dt_bias, nullptr, 0);
  // 3) single-pass persistent scan (128 blocks, double-buffered LDS)
  scan_seq<<<128, 256, 0, stream>>>(xs, dts, bcb, A_log, rope, yb, fstate);
  // 4) gate + LN (bf16 out)
  gate_ln<<<TOK, 256, 0, stream>>>(yb, zb, ln_w, ln_b, lnb);
  // 5) out = ln @ W_out^T, split-K=2 (512 blocks), partials into Pk (dead xs region)
  gemm_mfma<16, 16, 2, false><<<16 * 16 * 2, 256, 0, stream>>>(
      lnb, wob, DI, nullptr, nullptr, nullptr, nullptr, nullptr, nullptr, Pk, DM);
  // 6) out = Pk0 + Pk1
  addk<<<(TOK * DM) / 1024, 256, 0, stream>>>(Pk, Pk + (size_t)TOK * DM, out);
}